// Round 2
// baseline (1317.192 us; speedup 1.0000x reference)
//
#include <hip/hip_runtime.h>

typedef unsigned short u16;
typedef unsigned int u32;
typedef __attribute__((ext_vector_type(8))) short short8;
typedef __attribute__((ext_vector_type(4))) float f32x4;

#define XS 264   // LDS activation row stride in u16 (256 + 8 pad)

__device__ __forceinline__ float b2f(u16 u) {
    return __builtin_bit_cast(float, (u32)u << 16);
}
__device__ __forceinline__ u16 f2b(float f) {   // RNE fp32 -> bf16
    u32 x = __builtin_bit_cast(u32, f);
    x += 0x7fffu + ((x >> 16) & 1u);
    return (u16)(x >> 16);
}

// ---------------- workspace layout (units: floats from ws base) ----------------
#define WS_LOSS   0           // 1 float
#define WS_ENORM  16          // 8192
#define WS_BD1    8224        // 4096*8 floats
#define WS_BD2    40992       // 4096*8
#define WS_BI1    73760       // 4096*8 ints
#define WS_BI2    106528      // 4096*8 ints
#define WS_RESID  139296      // 4096*128
#define WS_ZQSUM  663584      // 4096*128
#define WS_ZCUR   1187872     // 4096*128
#define WS_BETAS  1712160     // u16 region: 5*4096*256 u16
#define WS_W0PAD  4333600     // u16: 256*64
#define WS_DWH    4341792     // u16: 4*256*256
// total ~4.48M floats ~ 18 MB

// ---------------------------------------------------------------- e-norms (fp32)
__global__ __launch_bounds__(64) void enorm_kernel(const float* __restrict__ vq,
                                                   float* __restrict__ enorm) {
    int code = blockIdx.x;            // 8192 = S*K
    int lane = threadIdx.x;
    const float* e = vq + (size_t)code * 128;
    float a = e[lane], b = e[lane + 64];
    float v = a * a + b * b;
    #pragma unroll
    for (int off = 32; off; off >>= 1) v += __shfl_down(v, off);
    if (lane == 0) enorm[code] = v;
}

// ---------------------------------------------------------------- W0 pad 42->64, fp32 -> bf16
__global__ __launch_bounds__(256) void padw0_kernel(const float* __restrict__ W0,
                                                    u16* __restrict__ w0pad) {
    int i = blockIdx.x * 256 + threadIdx.x;   // 16384
    int row = i >> 6, k = i & 63;
    w0pad[i] = (k < 42) ? f2b(W0[row * 42 + k]) : (u16)0;
}

// ---------------------------------------------------------------- dec_Wh fp32 -> bf16
__global__ __launch_bounds__(256) void dwh_kernel(const float* __restrict__ Wh,
                                                  u16* __restrict__ dwh) {
    int i = blockIdx.x * 256 + threadIdx.x;   // 262144
    dwh[i] = f2b(Wh[i]);
}

// ---------------------------------------------------------------- VQ init (stage 0 state)
__global__ __launch_bounds__(256) void vqinit_kernel(const int* __restrict__ lidx,
                                                     const float* __restrict__ latents,
                                                     float* __restrict__ resid,
                                                     float* __restrict__ zqsum,
                                                     float* __restrict__ zcur) {
    int i = blockIdx.x * 256 + threadIdx.x;   // 524288
    int r = i >> 7, d = i & 127;
    float v = latents[(size_t)lidx[r] * 512 + d];
    resid[i] = v; zcur[i] = v; zqsum[i] = 0.f;
}

// ---------------------------------------------------------------- VQ distance pass
// grid (64 rowgroups, 8 code chunks) x 256. lane = row, z in 128 VGPRs,
// wave-uniform code pointer (broadcast loads). Tracks top-2 per row-chunk.
__global__ __launch_bounds__(256, 2) void vqdist_kernel(int s,
        const float* __restrict__ zcur, const float* __restrict__ vq,
        const float* __restrict__ enorm,
        float* __restrict__ bd1, float* __restrict__ bd2,
        int* __restrict__ bi1, int* __restrict__ bi2) {
    int lane = threadIdx.x & 63;
    int w = __builtin_amdgcn_readfirstlane(threadIdx.x >> 6);
    int r = blockIdx.x * 64 + lane;
    int chunk = blockIdx.y;

    float zc[128];
    {
        const float4* z4 = (const float4*)(zcur + (size_t)r * 128);
        #pragma unroll
        for (int c = 0; c < 32; ++c) {
            float4 v = z4[c];
            zc[4*c] = v.x; zc[4*c+1] = v.y; zc[4*c+2] = v.z; zc[4*c+3] = v.w;
        }
    }
    int kbase = chunk * 256 + w * 64;
    const float* cb = vq + ((size_t)s * 2048 + kbase) * 128;
    const float* en = enorm + s * 2048 + kbase;

    float b1 = 3.4e38f, b2v = 3.4e38f; int i1 = 0, i2 = 0;
    for (int k0 = 0; k0 < 64; ++k0) {
        const float4* e4 = (const float4*)(cb + (size_t)k0 * 128);
        float d0 = 0.f, d1 = 0.f, d2 = 0.f, d3 = 0.f;
        #pragma unroll
        for (int c = 0; c < 32; ++c) {
            float4 e = e4[c];
            d0 += e.x * zc[4*c];   d1 += e.y * zc[4*c+1];
            d2 += e.z * zc[4*c+2]; d3 += e.w * zc[4*c+3];
        }
        float dist = en[k0] - 2.f * ((d0 + d1) + (d2 + d3));
        int k = kbase + k0;
        if (dist < b1)       { b2v = b1; i2 = i1; b1 = dist; i1 = k; }
        else if (dist < b2v) { b2v = dist; i2 = k; }
    }

    __shared__ float rd1[4][64], rd2[4][64];
    __shared__ int   ri1[4][64], ri2[4][64];
    rd1[w][lane] = b1; rd2[w][lane] = b2v; ri1[w][lane] = i1; ri2[w][lane] = i2;
    __syncthreads();
    if (w == 0) {
        #pragma unroll
        for (int ww = 1; ww < 4; ++ww) {   // ascending code order; strict < keeps lowest index
            float c1 = rd1[ww][lane], c2 = rd2[ww][lane];
            int   j1 = ri1[ww][lane], j2 = ri2[ww][lane];
            if (c1 < b1) {
                float n2; int ni2;
                if (b1 <= c2) { n2 = b1; ni2 = i1; } else { n2 = c2; ni2 = j2; }
                b1 = c1; i1 = j1; b2v = n2; i2 = ni2;
            } else if (c1 < b2v) { b2v = c1; i2 = j1; }
        }
        size_t o = (size_t)r * 8 + chunk;
        bd1[o] = b1; bd2[o] = b2v; bi1[o] = i1; bi2[o] = i2;
    }
}

// ---------------------------------------------------------------- VQ select + state update
// one block per row, 128 threads = dims. fp64 rescore of near-ties.
__global__ __launch_bounds__(128) void vqsel_kernel(int s,
        const int* __restrict__ lidx, const float* __restrict__ latents,
        const float* __restrict__ vq,
        const float* __restrict__ bd1, const float* __restrict__ bd2,
        const int* __restrict__ bi1, const int* __restrict__ bi2,
        float* __restrict__ resid, float* __restrict__ zqsum,
        float* __restrict__ zcur, float* __restrict__ lossp) {
    int r = blockIdx.x, t = threadIdx.x;
    __shared__ int ssel, scand;
    __shared__ double p1[2], p2[2];
    __shared__ float lr[2];

    if (t == 0) {
        float b1 = 3.4e38f, b2v = 3.4e38f; int i1 = 0, i2 = 0;
        for (int c = 0; c < 8; ++c) {       // ascending chunk = ascending code index
            size_t o = (size_t)r * 8 + c;
            float c1 = bd1[o], c2 = bd2[o]; int j1 = bi1[o], j2 = bi2[o];
            if (c1 < b1) {
                float n2; int ni2;
                if (b1 <= c2) { n2 = b1; ni2 = i1; } else { n2 = c2; ni2 = j2; }
                b1 = c1; i1 = j1; b2v = n2; i2 = ni2;
            } else if (c1 < b2v) { b2v = c1; i2 = j1; }
        }
        ssel = i1;
        scand = (b2v - b1 < 1e-2f) ? i2 : -1;   // near-tie: fp64 rescore
    }
    __syncthreads();
    int c2i = scand;
    float zf = zcur[(size_t)r * 128 + t];
    if (c2i >= 0) {
        int k1 = ssel;
        double z  = (double)zf;
        double e1 = (double)vq[((size_t)s * 2048 + k1) * 128 + t];
        double e2 = (double)vq[((size_t)s * 2048 + c2i) * 128 + t];
        double t1 = e1 * e1 - 2.0 * e1 * z;
        double t2 = e2 * e2 - 2.0 * e2 * z;
        #pragma unroll
        for (int off = 32; off; off >>= 1) {
            t1 += __shfl_down(t1, off);
            t2 += __shfl_down(t2, off);
        }
        if ((t & 63) == 0) { p1[t >> 6] = t1; p2[t >> 6] = t2; }
        __syncthreads();
        if (t == 0) {
            double d1 = p1[0] + p1[1], d2v = p2[0] + p2[1];
            if (d2v < d1 || (d2v == d1 && c2i < ssel)) ssel = c2i;
        }
        __syncthreads();
    }
    int k = ssel;
    float e = vq[((size_t)s * 2048 + k) * 128 + t];
    float diff = e - zf;
    float l = diff * diff;
    #pragma unroll
    for (int off = 32; off; off >>= 1) l += __shfl_down(l, off);
    if ((t & 63) == 0) lr[t >> 6] = l;

    float nz = zqsum[(size_t)r * 128 + t] + e;
    zqsum[(size_t)r * 128 + t] = nz;
    if (s < 3) {
        float rs = resid[(size_t)r * 128 + t]
                 + latents[((size_t)lidx[r] * 4 + (s + 1)) * 128 + t];
        resid[(size_t)r * 128 + t] = rs;
        zcur[(size_t)r * 128 + t] = rs - nz;
    }
    __syncthreads();
    if (t == 0) atomicAdd(lossp, lr[0] + lr[1]);
}

// ---------------------------------------------------------------- betas (fp32 VALU -> bf16)
// grid (256,5) x 128: 16 batch rows/block, thread t -> h = t and t+128
__global__ __launch_bounds__(128) void betas_kernel(const float* __restrict__ zqsum,
                                                    const float* __restrict__ mod_W,
                                                    const float* __restrict__ mod_b,
                                                    u16* __restrict__ betas) {
    int bg = blockIdx.x, l = blockIdx.y, t = threadIdx.x;
    __shared__ float zq[16][128];
    for (int u = t; u < 2048; u += 128) ((float*)zq)[u] = zqsum[(size_t)bg * 2048 + u];
    __syncthreads();

    float acc0[16], acc1[16];
    #pragma unroll
    for (int i = 0; i < 16; ++i) { acc0[i] = 0.f; acc1[i] = 0.f; }

    const float4* w0 = (const float4*)(mod_W + ((size_t)l * 256 + t) * 128);
    const float4* w1 = (const float4*)(mod_W + ((size_t)l * 256 + t + 128) * 128);
    #pragma unroll
    for (int c = 0; c < 32; ++c) {
        float4 wa = w0[c], wb = w1[c];
        #pragma unroll
        for (int bb = 0; bb < 16; ++bb) {
            float4 za = *(const float4*)&zq[bb][c * 4];
            acc0[bb] += wa.x * za.x + wa.y * za.y + wa.z * za.z + wa.w * za.w;
            acc1[bb] += wb.x * za.x + wb.y * za.y + wb.z * za.z + wb.w * za.w;
        }
    }
    float bias0 = mod_b[l * 256 + t], bias1 = mod_b[l * 256 + t + 128];
    #pragma unroll
    for (int bb = 0; bb < 16; ++bb) {
        size_t o = ((size_t)l * 4096 + bg * 16 + bb) * 256;
        betas[o + t]       = f2b(acc0[bb] + bias0);
        betas[o + t + 128] = f2b(acc1[bb] + bias1);
    }
}

// ---------------------------------------------------------------- fused MLP (bf16 MFMA)
// one block per image (4096 blocks), 256 threads = 4 waves.
// 64 point-rows resident in LDS (bf16); wave w computes cols [w*64, w*64+64).
__global__ __launch_bounds__(256, 2) void mlp_kernel(const float* __restrict__ coords,
                                                     const u16* __restrict__ w0pad,
                                                     const float* __restrict__ dec_b0,
                                                     const u16* __restrict__ dwh,
                                                     const float* __restrict__ dec_bh,
                                                     const float* __restrict__ last_W,
                                                     const float* __restrict__ last_b,
                                                     const u16* __restrict__ betas,
                                                     float* __restrict__ out) {
    __shared__ __align__(16) u16 X[64 * XS];
    int b = blockIdx.x;
    int tid = threadIdx.x;
    int lane = tid & 63, wv = tid >> 6;
    int q = lane >> 4, r16 = lane & 15;
    int nbase = wv * 64;

    // positional encoding: enc = [c0,c1, sin(c0*f), sin(c1*f), cos(c0*f), cos(c1*f)], pad to 64
    {
        int m = tid & 63, g = tid >> 6;
        float c0 = coords[((b << 6) + m) * 2 + 0];
        float c1 = coords[((b << 6) + m) * 2 + 1];
        u16* row = &X[m * XS];
        if (g == 0) {
            row[0] = f2b(c0); row[1] = f2b(c1);
            #pragma unroll
            for (int c = 42; c < 64; ++c) row[c] = 0;
            #pragma unroll
            for (int f = 0; f < 10; ++f) {
                float pf = 3.14159265358979323846f * (float)(1 << f);
                row[32 + f] = f2b(cosf(c1 * pf));
            }
        } else if (g == 1) {
            #pragma unroll
            for (int f = 0; f < 10; ++f) {
                float pf = 3.14159265358979323846f * (float)(1 << f);
                row[2 + f] = f2b(sinf(c0 * pf));
            }
        } else if (g == 2) {
            #pragma unroll
            for (int f = 0; f < 10; ++f) {
                float pf = 3.14159265358979323846f * (float)(1 << f);
                row[12 + f] = f2b(sinf(c1 * pf));
            }
        } else {
            #pragma unroll
            for (int f = 0; f < 10; ++f) {
                float pf = 3.14159265358979323846f * (float)(1 << f);
                row[22 + f] = f2b(cosf(c0 * pf));
            }
        }
    }
    __syncthreads();

    f32x4 acc[4][4];

    auto gemm = [&](const u16* W, int Kdim, int wstride) {
        #pragma unroll
        for (int mt = 0; mt < 4; ++mt)
            #pragma unroll
            for (int nt = 0; nt < 4; ++nt) {
                f32x4 z = {0.f, 0.f, 0.f, 0.f};
                acc[mt][nt] = z;
            }
        for (int kc = 0; kc < Kdim; kc += 32) {
            short8 afr[4], bfr[4];
            #pragma unroll
            for (int mt = 0; mt < 4; ++mt)
                afr[mt] = *(const short8*)&X[(mt * 16 + r16) * XS + kc + q * 8];
            #pragma unroll
            for (int nt = 0; nt < 4; ++nt)
                bfr[nt] = *(const short8*)&W[(size_t)(nbase + nt * 16 + r16) * wstride + kc + q * 8];
            #pragma unroll
            for (int mt = 0; mt < 4; ++mt)
                #pragma unroll
                for (int nt = 0; nt < 4; ++nt)
                    acc[mt][nt] = __builtin_amdgcn_mfma_f32_16x16x32_bf16(
                        afr[mt], bfr[nt], acc[mt][nt], 0, 0, 0);
        }
    };

    auto epilogue = [&](const float* bias, const u16* beta_l) {
        __syncthreads();   // all waves done reading X
        #pragma unroll
        for (int nt = 0; nt < 4; ++nt) {
            int n = nbase + nt * 16 + r16;
            float bv = bias[n] + b2f(beta_l[n]);
            #pragma unroll
            for (int mt = 0; mt < 4; ++mt) {
                #pragma unroll
                for (int rr = 0; rr < 4; ++rr) {
                    int m = mt * 16 + q * 4 + rr;
                    float v = acc[mt][nt][rr] + bv;
                    v = fmaxf(v, 0.f);
                    X[m * XS + n] = f2b(v);
                }
            }
        }
        __syncthreads();
    };

    gemm(w0pad, 64, 64);
    epilogue(dec_b0, betas + (size_t)b * 256);

    for (int l = 1; l < 5; ++l) {
        gemm(dwh + (size_t)(l - 1) * 65536, 256, 256);
        epilogue(dec_bh + (size_t)(l - 1) * 256, betas + ((size_t)l * 4096 + b) * 256);
    }

    // last layer: 64 rows x 3 outputs, fp32 VALU, fp32 store
    if (tid < 192) {
        int rr = tid / 3, v = tid - rr * 3;
        float a = 0.f;
        #pragma unroll
        for (int d = 0; d < 256; d += 8) {
            #pragma unroll
            for (int j = 0; j < 8; ++j)
                a += b2f(X[rr * XS + d + j]) * last_W[v * 256 + d + j];
        }
        out[((size_t)b * 64 + rr) * 3 + v] = a + last_b[v];
    }
}

// ---------------------------------------------------------------- loss finalize (fp32 out)
__global__ void finalize_kernel(const float* __restrict__ loss, float* __restrict__ out) {
    out[786432] = 0.25f * loss[0] * (1.f / (4096.f * 128.f));
}

extern "C" void kernel_launch(void* const* d_in, const int* in_sizes, int n_in,
                              void* d_out, int out_size, void* d_ws, size_t ws_size,
                              hipStream_t stream) {
    const float* coords  = (const float*)d_in[0];
    const int*   lidx    = (const int*)d_in[1];
    const float* latents = (const float*)d_in[2];
    const float* vq      = (const float*)d_in[3];
    const float* mod_W   = (const float*)d_in[4];
    const float* mod_b   = (const float*)d_in[5];
    const float* dec_W0  = (const float*)d_in[6];
    const float* dec_b0  = (const float*)d_in[7];
    const float* dec_Wh  = (const float*)d_in[8];
    const float* dec_bh  = (const float*)d_in[9];
    const float* last_W  = (const float*)d_in[10];
    const float* last_b  = (const float*)d_in[11];
    float* out = (float*)d_out;

    float* wsf   = (float*)d_ws;
    float* lossp = wsf + WS_LOSS;
    float* enorm = wsf + WS_ENORM;
    float* bd1   = wsf + WS_BD1;
    float* bd2   = wsf + WS_BD2;
    int*   bi1   = (int*)(wsf + WS_BI1);
    int*   bi2   = (int*)(wsf + WS_BI2);
    float* resid = wsf + WS_RESID;
    float* zqsum = wsf + WS_ZQSUM;
    float* zcur  = wsf + WS_ZCUR;
    u16*   betas = (u16*)(wsf + WS_BETAS);
    u16*   w0pad = (u16*)(wsf + WS_W0PAD);
    u16*   dwh   = (u16*)(wsf + WS_DWH);

    hipMemsetAsync(lossp, 0, 4, stream);
    enorm_kernel<<<8192, 64, 0, stream>>>(vq, enorm);
    padw0_kernel<<<64, 256, 0, stream>>>(dec_W0, w0pad);
    dwh_kernel<<<1024, 256, 0, stream>>>(dec_Wh, dwh);
    vqinit_kernel<<<2048, 256, 0, stream>>>(lidx, latents, resid, zqsum, zcur);
    for (int s = 0; s < 4; ++s) {
        vqdist_kernel<<<dim3(64, 8), 256, 0, stream>>>(s, zcur, vq, enorm, bd1, bd2, bi1, bi2);
        vqsel_kernel<<<4096, 128, 0, stream>>>(s, lidx, latents, vq, bd1, bd2, bi1, bi2,
                                               resid, zqsum, zcur, lossp);
    }
    betas_kernel<<<dim3(256, 5), 128, 0, stream>>>(zqsum, mod_W, mod_b, betas);
    mlp_kernel<<<4096, 256, 0, stream>>>(coords, w0pad, dec_b0, dwh, dec_bh,
                                         last_W, last_b, betas, out);
    finalize_kernel<<<1, 1, 0, stream>>>(lossp, out);
}

// Round 4
// 1181.725 us; speedup vs baseline: 1.1146x; 1.1146x over previous
//
#include <hip/hip_runtime.h>

typedef unsigned short u16;
typedef unsigned int u32;
typedef __attribute__((ext_vector_type(8))) short short8;
typedef __attribute__((ext_vector_type(4))) float f32x4;

#define XS 264   // LDS activation row stride in u16 (256 + 8 pad)

__device__ __forceinline__ float b2f(u16 u) {
    return __builtin_bit_cast(float, (u32)u << 16);
}
__device__ __forceinline__ u16 f2b(float f) {   // RNE fp32 -> bf16
    u32 x = __builtin_bit_cast(u32, f);
    x += 0x7fffu + ((x >> 16) & 1u);
    return (u16)(x >> 16);
}

// ---------------- workspace layout (units: floats from ws base) ----------------
// betas is 5*4096*256 u16 = 5,242,880 u16 = 2,621,440 floats  (round-3 bug: had half)
#define WS_LPART  0           // 512 floats (per-block loss partials)
#define WS_ENORM  512         // 8192
#define WS_ZQSUM  8704        // 4096*128 = 524288 -> ends 532992
#define WS_BETAS  532992      // u16: 5*4096*256 = 2621440 floats -> ends 3154432
#define WS_W0PAD  3154432     // u16: 256*64 = 8192 floats -> ends 3162624
#define WS_DWH    3162624     // u16: 4*256*256 = 131072 floats -> ends 3293696
// total ~3.29M floats ~ 13.2 MB

// ---------------------------------------------------------------- e-norms (fp32)
__global__ __launch_bounds__(64) void enorm_kernel(const float* __restrict__ vq,
                                                   float* __restrict__ enorm) {
    int code = blockIdx.x;            // 8192 = S*K
    int lane = threadIdx.x;
    const float* e = vq + (size_t)code * 128;
    float a = e[lane], b = e[lane + 64];
    float v = a * a + b * b;
    #pragma unroll
    for (int off = 32; off; off >>= 1) v += __shfl_down(v, off);
    if (lane == 0) enorm[code] = v;
}

// ---------------------------------------------------------------- W0 pad 42->64, fp32 -> bf16
__global__ __launch_bounds__(256) void padw0_kernel(const float* __restrict__ W0,
                                                    u16* __restrict__ w0pad) {
    int i = blockIdx.x * 256 + threadIdx.x;   // 16384
    int row = i >> 6, k = i & 63;
    w0pad[i] = (k < 42) ? f2b(W0[row * 42 + k]) : (u16)0;
}

// ---------------------------------------------------------------- dec_Wh fp32 -> bf16
__global__ __launch_bounds__(256) void dwh_kernel(const float* __restrict__ Wh,
                                                  u16* __restrict__ dwh) {
    int i = blockIdx.x * 256 + threadIdx.x;   // 262144
    dwh[i] = f2b(Wh[i]);
}

// ---------------------------------------------------------------- fused residual VQ (all 4 stages)
// 512 blocks x 256 threads; block handles 8 rows. thread: b = tid&7, slice = tid>>3.
// Per stage: thread scans codes [slice*64, slice*64+64) against its row's z_cur
// (held in 128 VGPRs). State resid/zqsum/zcur lives in LDS with reference-exact
// fp32 rounding order. No atomics: per-block loss partial -> lpartial[block].
__global__ __launch_bounds__(256, 2) void vq_kernel(const int* __restrict__ lidx,
                                                    const float* __restrict__ latents,
                                                    const float* __restrict__ vq,
                                                    const float* __restrict__ enorm,
                                                    float* __restrict__ zqsum_g,
                                                    float* __restrict__ lpartial) {
    int tid = threadIdx.x;
    int b = tid & 7, slice = tid >> 3;
    int gb = blockIdx.x * 8 + b;

    __shared__ float s_resid[8][128];
    __shared__ float s_zqsum[8][128];
    __shared__ float s_zcur[8][128];
    __shared__ float rd1[32][8], rd2[32][8];
    __shared__ int   ri1[32][8], ri2[32][8];
    __shared__ int   sel[8], cand[8];
    __shared__ float lossb[8];

    size_t li = (size_t)lidx[gb];

    // stage-0 init: resid = zcur = lat[:,0,:], zqsum = 0  (thread owns dims slice*4..+3)
    {
        float4 v = ((const float4*)latents)[li * 128 + slice];
        *(float4*)&s_resid[b][slice * 4] = v;
        *(float4*)&s_zcur[b][slice * 4]  = v;
        float4 z = {0.f, 0.f, 0.f, 0.f};
        *(float4*)&s_zqsum[b][slice * 4] = z;
    }
    float loss_local = 0.f;   // valid on tid<8
    __syncthreads();

    for (int s = 0; s < 4; ++s) {
        // z_cur -> registers (LDS broadcast across the 32 slice-threads of row b)
        float zc[128];
        #pragma unroll
        for (int c = 0; c < 32; ++c) {
            float4 v = *(const float4*)&s_zcur[b][c * 4];
            zc[4*c] = v.x; zc[4*c+1] = v.y; zc[4*c+2] = v.z; zc[4*c+3] = v.w;
        }

        const float* cb = vq + ((size_t)s * 2048 + slice * 64) * 128;
        const float* en = enorm + s * 2048 + slice * 64;

        float b1 = 3.4e38f, b2v = 3.4e38f; int i1 = 0, i2 = 0;
        for (int k0 = 0; k0 < 64; ++k0) {
            const float4* e4 = (const float4*)(cb + (size_t)k0 * 128);
            float d0 = 0.f, d1 = 0.f, d2 = 0.f, d3 = 0.f;
            #pragma unroll
            for (int c = 0; c < 32; ++c) {
                float4 e = e4[c];
                d0 += e.x * zc[4*c];   d1 += e.y * zc[4*c+1];
                d2 += e.z * zc[4*c+2]; d3 += e.w * zc[4*c+3];
            }
            float dist = en[k0] - 2.f * ((d0 + d1) + (d2 + d3));
            int k = slice * 64 + k0;
            if (dist < b1)       { b2v = b1; i2 = i1; b1 = dist; i1 = k; }
            else if (dist < b2v) { b2v = dist; i2 = k; }
        }
        rd1[slice][b] = b1; rd2[slice][b] = b2v;
        ri1[slice][b] = i1; ri2[slice][b] = i2;
        __syncthreads();

        if (tid < 8) {   // b == tid, merge 32 slice top-2s (ascending slice = ascending k)
            float m1 = 3.4e38f, m2 = 3.4e38f; int j1 = 0, j2 = 0;
            for (int sl = 0; sl < 32; ++sl) {
                float c1 = rd1[sl][tid], c2 = rd2[sl][tid];
                int   k1 = ri1[sl][tid], k2 = ri2[sl][tid];
                if (c1 < m1) {
                    float n2; int n2i;
                    if (m1 <= c2) { n2 = m1; n2i = j1; } else { n2 = c2; n2i = k2; }
                    m1 = c1; j1 = k1; m2 = n2; j2 = n2i;
                } else if (c1 < m2) { m2 = c1; j2 = k1; }
            }
            sel[tid]  = j1;
            cand[tid] = (m2 - m1 < 1e-2f) ? j2 : -1;
        }
        __syncthreads();

        if (tid < 8 && cand[tid] >= 0) {   // fp64 rescore of near-tie
            int k1 = sel[tid], k2 = cand[tid];
            const float* e1p = vq + ((size_t)s * 2048 + k1) * 128;
            const float* e2p = vq + ((size_t)s * 2048 + k2) * 128;
            double t1 = 0.0, t2 = 0.0;
            for (int d = 0; d < 128; ++d) {
                double z  = (double)s_zcur[tid][d];
                double e1 = (double)e1p[d], e2 = (double)e2p[d];
                t1 += e1 * e1 - 2.0 * e1 * z;
                t2 += e2 * e2 - 2.0 * e2 * z;
            }
            if (t2 < t1 || (t2 == t1 && k2 < k1)) sel[tid] = k2;
        }
        __syncthreads();

        int k = sel[b];
        float4 e = ((const float4*)vq)[((size_t)s * 2048 + k) * 32 + slice];
        // loss partial: (e - z_cur)^2 on owned dims
        {
            int d = slice * 4;
            float f0 = e.x - zc[d], f1 = e.y - zc[d+1];
            float f2 = e.z - zc[d+2], f3 = e.w - zc[d+3];
            rd1[slice][b] = f0*f0 + f1*f1 + f2*f2 + f3*f3;
        }
        // state update with reference rounding order:
        // zqsum += e; resid += lat[s+1]; zcur = resid - zqsum
        {
            int d = slice * 4;
            float4 zq = *(float4*)&s_zqsum[b][d];
            zq.x += e.x; zq.y += e.y; zq.z += e.z; zq.w += e.w;
            *(float4*)&s_zqsum[b][d] = zq;
            if (s < 3) {
                float4 lv = ((const float4*)latents)[li * 128 + (size_t)(s + 1) * 32 + slice];
                float4 rs = *(float4*)&s_resid[b][d];
                rs.x += lv.x; rs.y += lv.y; rs.z += lv.z; rs.w += lv.w;
                *(float4*)&s_resid[b][d] = rs;
                float4 zcn;
                zcn.x = rs.x - zq.x; zcn.y = rs.y - zq.y;
                zcn.z = rs.z - zq.z; zcn.w = rs.w - zq.w;
                *(float4*)&s_zcur[b][d] = zcn;
            }
        }
        __syncthreads();
        if (tid < 8) {
            float l = 0.f;
            for (int sl = 0; sl < 32; ++sl) l += rd1[sl][tid];
            loss_local += l;
        }
        __syncthreads();
    }

    // write z_q_sum (coalesced) and per-block loss partial
    for (int u = tid; u < 1024; u += 256)
        zqsum_g[(size_t)blockIdx.x * 1024 + u] = ((const float*)s_zqsum)[u];
    if (tid < 8) lossb[tid] = loss_local;
    __syncthreads();
    if (tid == 0) {
        float l = 0.f;
        #pragma unroll
        for (int i = 0; i < 8; ++i) l += lossb[i];
        lpartial[blockIdx.x] = l;
    }
}

// ---------------------------------------------------------------- betas (fp32 VALU -> bf16)
// grid (256,5) x 128: 16 batch rows/block, thread t -> h = t and t+128
__global__ __launch_bounds__(128) void betas_kernel(const float* __restrict__ zqsum,
                                                    const float* __restrict__ mod_W,
                                                    const float* __restrict__ mod_b,
                                                    u16* __restrict__ betas) {
    int bg = blockIdx.x, l = blockIdx.y, t = threadIdx.x;
    __shared__ float zq[16][128];
    for (int u = t; u < 2048; u += 128) ((float*)zq)[u] = zqsum[(size_t)bg * 2048 + u];
    __syncthreads();

    float acc0[16], acc1[16];
    #pragma unroll
    for (int i = 0; i < 16; ++i) { acc0[i] = 0.f; acc1[i] = 0.f; }

    const float4* w0 = (const float4*)(mod_W + ((size_t)l * 256 + t) * 128);
    const float4* w1 = (const float4*)(mod_W + ((size_t)l * 256 + t + 128) * 128);
    #pragma unroll
    for (int c = 0; c < 32; ++c) {
        float4 wa = w0[c], wb = w1[c];
        #pragma unroll
        for (int bb = 0; bb < 16; ++bb) {
            float4 za = *(const float4*)&zq[bb][c * 4];
            acc0[bb] += wa.x * za.x + wa.y * za.y + wa.z * za.z + wa.w * za.w;
            acc1[bb] += wb.x * za.x + wb.y * za.y + wb.z * za.z + wb.w * za.w;
        }
    }
    float bias0 = mod_b[l * 256 + t], bias1 = mod_b[l * 256 + t + 128];
    #pragma unroll
    for (int bb = 0; bb < 16; ++bb) {
        size_t o = ((size_t)l * 4096 + bg * 16 + bb) * 256;
        betas[o + t]       = f2b(acc0[bb] + bias0);
        betas[o + t + 128] = f2b(acc1[bb] + bias1);
    }
}

// ---------------------------------------------------------------- fused MLP (bf16 MFMA)
// one block per image (4096 blocks), 256 threads = 4 waves; wave w covers weight
// cols [w*64, w*64+64). MFMA operands: A = weight rows (global), B = activation
// rows (LDS) -> D row dim = weight col (q*4+rr), col dim = activation row (r16),
// so each lane's 4 rr-values are consecutive n at fixed m: epilogue = ds_write_b64.
__global__ __launch_bounds__(256, 4) void mlp_kernel(const float* __restrict__ coords,
                                                     const u16* __restrict__ w0pad,
                                                     const float* __restrict__ dec_b0,
                                                     const u16* __restrict__ dwh,
                                                     const float* __restrict__ dec_bh,
                                                     const float* __restrict__ last_W,
                                                     const float* __restrict__ last_b,
                                                     const u16* __restrict__ betas,
                                                     float* __restrict__ out) {
    __shared__ __align__(16) u16 X[64 * XS];
    int b = blockIdx.x;
    int tid = threadIdx.x;
    int lane = tid & 63, wv = tid >> 6;
    int q = lane >> 4, r16 = lane & 15;
    int nbase = wv * 64;

    // positional encoding: enc = [c0,c1, sin(c0*f), sin(c1*f), cos(c0*f), cos(c1*f)], pad to 64
    {
        int m = tid & 63, g = tid >> 6;
        float c0 = coords[((b << 6) + m) * 2 + 0];
        float c1 = coords[((b << 6) + m) * 2 + 1];
        u16* row = &X[m * XS];
        if (g == 0) {
            row[0] = f2b(c0); row[1] = f2b(c1);
            #pragma unroll
            for (int c = 42; c < 64; ++c) row[c] = 0;
            #pragma unroll
            for (int f = 0; f < 10; ++f) {
                float pf = 3.14159265358979323846f * (float)(1 << f);
                row[32 + f] = f2b(cosf(c1 * pf));
            }
        } else if (g == 1) {
            #pragma unroll
            for (int f = 0; f < 10; ++f) {
                float pf = 3.14159265358979323846f * (float)(1 << f);
                row[2 + f] = f2b(sinf(c0 * pf));
            }
        } else if (g == 2) {
            #pragma unroll
            for (int f = 0; f < 10; ++f) {
                float pf = 3.14159265358979323846f * (float)(1 << f);
                row[12 + f] = f2b(sinf(c1 * pf));
            }
        } else {
            #pragma unroll
            for (int f = 0; f < 10; ++f) {
                float pf = 3.14159265358979323846f * (float)(1 << f);
                row[22 + f] = f2b(cosf(c0 * pf));
            }
        }
    }
    __syncthreads();

    f32x4 acc[4][4];   // [nt][mt]

    auto gemm = [&](const u16* W, int Kdim, int wstride) {
        #pragma unroll
        for (int nt = 0; nt < 4; ++nt)
            #pragma unroll
            for (int mt = 0; mt < 4; ++mt) {
                f32x4 z = {0.f, 0.f, 0.f, 0.f};
                acc[nt][mt] = z;
            }
        for (int kc = 0; kc < Kdim; kc += 32) {
            short8 afr[4], bfr[4];
            #pragma unroll
            for (int nt = 0; nt < 4; ++nt)   // weights
                afr[nt] = *(const short8*)&W[(size_t)(nbase + nt * 16 + r16) * wstride + kc + q * 8];
            #pragma unroll
            for (int mt = 0; mt < 4; ++mt)   // activations
                bfr[mt] = *(const short8*)&X[(mt * 16 + r16) * XS + kc + q * 8];
            #pragma unroll
            for (int nt = 0; nt < 4; ++nt)
                #pragma unroll
                for (int mt = 0; mt < 4; ++mt)
                    acc[nt][mt] = __builtin_amdgcn_mfma_f32_16x16x32_bf16(
                        afr[nt], bfr[mt], acc[nt][mt], 0, 0, 0);
        }
    };

    auto epilogue = [&](const float* bias, const u16* beta_l) {
        // per-lane bias+beta for its 4 consecutive n per nt
        float bv[4][4];
        #pragma unroll
        for (int nt = 0; nt < 4; ++nt) {
            int n0 = nbase + nt * 16 + q * 4;
            float4 bs = *(const float4*)&bias[n0];
            bv[nt][0] = bs.x + b2f(beta_l[n0 + 0]);
            bv[nt][1] = bs.y + b2f(beta_l[n0 + 1]);
            bv[nt][2] = bs.z + b2f(beta_l[n0 + 2]);
            bv[nt][3] = bs.w + b2f(beta_l[n0 + 3]);
        }
        __syncthreads();   // all waves done reading X
        #pragma unroll
        for (int mt = 0; mt < 4; ++mt) {
            int m = mt * 16 + r16;
            #pragma unroll
            for (int nt = 0; nt < 4; ++nt) {
                int n0 = nbase + nt * 16 + q * 4;
                float v0 = fmaxf(acc[nt][mt][0] + bv[nt][0], 0.f);
                float v1 = fmaxf(acc[nt][mt][1] + bv[nt][1], 0.f);
                float v2 = fmaxf(acc[nt][mt][2] + bv[nt][2], 0.f);
                float v3 = fmaxf(acc[nt][mt][3] + bv[nt][3], 0.f);
                uint2 pk;
                pk.x = (u32)f2b(v0) | ((u32)f2b(v1) << 16);
                pk.y = (u32)f2b(v2) | ((u32)f2b(v3) << 16);
                *(uint2*)&X[m * XS + n0] = pk;
            }
        }
        __syncthreads();
    };

    gemm(w0pad, 64, 64);
    epilogue(dec_b0, betas + (size_t)b * 256);

    for (int l = 1; l < 5; ++l) {
        gemm(dwh + (size_t)(l - 1) * 65536, 256, 256);
        epilogue(dec_bh + (size_t)(l - 1) * 256, betas + ((size_t)l * 4096 + b) * 256);
    }

    // last layer: 64 rows x 3 outputs, fp32 VALU, fp32 store
    if (tid < 192) {
        int rr = tid / 3, v = tid - rr * 3;
        float a = 0.f;
        #pragma unroll
        for (int d = 0; d < 256; d += 8) {
            #pragma unroll
            for (int j = 0; j < 8; ++j)
                a += b2f(X[rr * XS + d + j]) * last_W[v * 256 + d + j];
        }
        out[((size_t)b * 64 + rr) * 3 + v] = a + last_b[v];
    }
}

// ---------------------------------------------------------------- loss finalize
__global__ __launch_bounds__(64) void finalize_kernel(const float* __restrict__ lpartial,
                                                      float* __restrict__ out) {
    int t = threadIdx.x;
    float s = 0.f;
    for (int i = t; i < 512; i += 64) s += lpartial[i];
    #pragma unroll
    for (int off = 32; off; off >>= 1) s += __shfl_down(s, off);
    if (t == 0) out[786432] = 0.25f * s * (1.f / (4096.f * 128.f));
}

extern "C" void kernel_launch(void* const* d_in, const int* in_sizes, int n_in,
                              void* d_out, int out_size, void* d_ws, size_t ws_size,
                              hipStream_t stream) {
    const float* coords  = (const float*)d_in[0];
    const int*   lidx    = (const int*)d_in[1];
    const float* latents = (const float*)d_in[2];
    const float* vq      = (const float*)d_in[3];
    const float* mod_W   = (const float*)d_in[4];
    const float* mod_b   = (const float*)d_in[5];
    const float* dec_W0  = (const float*)d_in[6];
    const float* dec_b0  = (const float*)d_in[7];
    const float* dec_Wh  = (const float*)d_in[8];
    const float* dec_bh  = (const float*)d_in[9];
    const float* last_W  = (const float*)d_in[10];
    const float* last_b  = (const float*)d_in[11];
    float* out = (float*)d_out;

    float* wsf      = (float*)d_ws;
    float* lpartial = wsf + WS_LPART;
    float* enorm    = wsf + WS_ENORM;
    float* zqsum    = wsf + WS_ZQSUM;
    u16*   betas    = (u16*)(wsf + WS_BETAS);
    u16*   w0pad    = (u16*)(wsf + WS_W0PAD);
    u16*   dwh      = (u16*)(wsf + WS_DWH);

    enorm_kernel<<<8192, 64, 0, stream>>>(vq, enorm);
    padw0_kernel<<<64, 256, 0, stream>>>(dec_W0, w0pad);
    dwh_kernel<<<1024, 256, 0, stream>>>(dec_Wh, dwh);
    vq_kernel<<<512, 256, 0, stream>>>(lidx, latents, vq, enorm, zqsum, lpartial);
    betas_kernel<<<dim3(256, 5), 128, 0, stream>>>(zqsum, mod_W, mod_b, betas);
    mlp_kernel<<<4096, 256, 0, stream>>>(coords, w0pad, dec_b0, dwh, dec_bh,
                                         last_W, last_b, betas, out);
    finalize_kernel<<<1, 64, 0, stream>>>(lpartial, out);
}

// Round 5
// 1154.447 us; speedup vs baseline: 1.1410x; 1.0236x over previous
//
#include <hip/hip_runtime.h>

typedef unsigned short u16;
typedef unsigned int u32;
typedef __attribute__((ext_vector_type(8))) short short8;
typedef __attribute__((ext_vector_type(4))) float f32x4;

#define XS 264   // LDS activation row stride in u16 (256 + 8 pad)

__device__ __forceinline__ float b2f(u16 u) {
    return __builtin_bit_cast(float, (u32)u << 16);
}
__device__ __forceinline__ u16 f2b(float f) {   // RNE fp32 -> bf16
    u32 x = __builtin_bit_cast(u32, f);
    x += 0x7fffu + ((x >> 16) & 1u);
    return (u16)(x >> 16);
}

// ---------------- workspace layout (units: floats from ws base) ----------------
#define WS_LPART  0           // 512 floats (per-block loss partials)
#define WS_ENORM  512         // 8192
#define WS_ZQSUM  8704        // 4096*128 = 524288 -> ends 532992
#define WS_BETAS  532992      // u16: 5*4096*256 = 2621440 floats -> ends 3154432
#define WS_W0PAD  3154432     // u16: 256*64 = 8192 floats -> ends 3162624
#define WS_DWH    3162624     // u16: 4*256*256 = 131072 floats -> ends 3293696
// total ~3.29M floats ~ 13.2 MB

// ---------------------------------------------------------------- e-norms (fp32)
__global__ __launch_bounds__(64) void enorm_kernel(const float* __restrict__ vq,
                                                   float* __restrict__ enorm) {
    int code = blockIdx.x;            // 8192 = S*K
    int lane = threadIdx.x;
    const float* e = vq + (size_t)code * 128;
    float a = e[lane], b = e[lane + 64];
    float v = a * a + b * b;
    #pragma unroll
    for (int off = 32; off; off >>= 1) v += __shfl_down(v, off);
    if (lane == 0) enorm[code] = v;
}

// ---------------------------------------------------------------- W0 pad 42->64, fp32 -> bf16
__global__ __launch_bounds__(256) void padw0_kernel(const float* __restrict__ W0,
                                                    u16* __restrict__ w0pad) {
    int i = blockIdx.x * 256 + threadIdx.x;   // 16384
    int row = i >> 6, k = i & 63;
    w0pad[i] = (k < 42) ? f2b(W0[row * 42 + k]) : (u16)0;
}

// ---------------------------------------------------------------- dec_Wh fp32 -> bf16
__global__ __launch_bounds__(256) void dwh_kernel(const float* __restrict__ Wh,
                                                  u16* __restrict__ dwh) {
    int i = blockIdx.x * 256 + threadIdx.x;   // 262144
    dwh[i] = f2b(Wh[i]);
}

// ---------------------------------------------------------------- fused residual VQ (all 4 stages)
// 512 blocks x 256 threads; block handles 8 rows.
// Scan layout: b = tid&7 (row), h = (tid>>3)&1 (dim half), s16 = tid>>4 (code slice
// of 128). Each thread holds 64 dims of z_cur in VGPRs (~95 regs total -> NO spill;
// round-4's zc[128] spilled 270 MB of scratch per dispatch). Half-dots combined with
// __shfl_xor(.,8) (partner differs only in h, same wave). Thread h tracks codes of
// parity h -> 32 top-2 lists/row, merged as before; fp64 rescore of <1e-2 ties keeps
// argmin exact. State resid/zqsum/zcur in LDS with reference fp32 rounding order.
__global__ __launch_bounds__(256) void vq_kernel(const int* __restrict__ lidx,
                                                 const float* __restrict__ latents,
                                                 const float* __restrict__ vq,
                                                 const float* __restrict__ enorm,
                                                 float* __restrict__ zqsum_g,
                                                 float* __restrict__ lpartial) {
    int tid = threadIdx.x;
    int b = tid & 7;
    int h = (tid >> 3) & 1;
    int s16 = tid >> 4;            // 0..15
    int ow = tid >> 3;             // 0..31: owns dims ow*4..+3 for state update
    int gb = blockIdx.x * 8 + b;

    __shared__ float s_resid[8][128];
    __shared__ float s_zqsum[8][128];
    __shared__ float s_zcur[8][128];
    __shared__ float rd1[32][8], rd2[32][8];
    __shared__ int   ri1[32][8], ri2[32][8];
    __shared__ int   sel[8], cand[8];
    __shared__ float lossb[8];

    size_t li = (size_t)lidx[gb];

    // stage-0 init (thread owns dims ow*4..+3)
    {
        float4 v = ((const float4*)latents)[li * 128 + ow];
        *(float4*)&s_resid[b][ow * 4] = v;
        *(float4*)&s_zcur[b][ow * 4]  = v;
        float4 z = {0.f, 0.f, 0.f, 0.f};
        *(float4*)&s_zqsum[b][ow * 4] = z;
    }
    float loss_local = 0.f;   // valid on tid<8
    __syncthreads();

    for (int s = 0; s < 4; ++s) {
        // 64 dims of z_cur -> registers (LDS broadcast)
        float zc[64];
        #pragma unroll
        for (int c = 0; c < 16; ++c) {
            float4 v = *(const float4*)&s_zcur[b][h * 64 + c * 4];
            zc[4*c] = v.x; zc[4*c+1] = v.y; zc[4*c+2] = v.z; zc[4*c+3] = v.w;
        }

        int kb = s16 * 128;
        const float* cb = vq + ((size_t)s * 2048 + kb) * 128 + h * 64;
        const float* en = enorm + s * 2048 + kb;

        float b1 = 3.4e38f, b2v = 3.4e38f; int i1 = 0, i2 = 0;
        for (int k0 = 0; k0 < 128; k0 += 2) {
            const float4* eA = (const float4*)(cb + (size_t)k0 * 128);
            const float4* eB = (const float4*)(cb + (size_t)(k0 + 1) * 128);
            float a0 = 0.f, a1 = 0.f, a2 = 0.f, a3 = 0.f;
            float c0 = 0.f, c1 = 0.f, c2 = 0.f, c3 = 0.f;
            #pragma unroll
            for (int c = 0; c < 16; ++c) {
                float4 ea = eA[c], eb = eB[c];
                a0 += ea.x * zc[4*c];   a1 += ea.y * zc[4*c+1];
                a2 += ea.z * zc[4*c+2]; a3 += ea.w * zc[4*c+3];
                c0 += eb.x * zc[4*c];   c1 += eb.y * zc[4*c+1];
                c2 += eb.z * zc[4*c+2]; c3 += eb.w * zc[4*c+3];
            }
            float pA = (a0 + a1) + (a2 + a3);
            float pB = (c0 + c1) + (c2 + c3);
            float fA = pA + __shfl_xor(pA, 8);
            float fB = pB + __shfl_xor(pB, 8);
            float dA = en[k0]     - 2.f * fA;
            float dB = en[k0 + 1] - 2.f * fB;
            float dT = h ? dB : dA;
            int   kT = kb + k0 + h;
            if (dT < b1)       { b2v = b1; i2 = i1; b1 = dT; i1 = kT; }
            else if (dT < b2v) { b2v = dT; i2 = kT; }
        }
        int vs = s16 * 2 + h;
        rd1[vs][b] = b1; rd2[vs][b] = b2v;
        ri1[vs][b] = i1; ri2[vs][b] = i2;
        __syncthreads();

        if (tid < 8) {   // b == tid, merge 32 top-2 lists
            float m1 = 3.4e38f, m2 = 3.4e38f; int j1 = 0, j2 = 0;
            for (int sl = 0; sl < 32; ++sl) {
                float d1c = rd1[sl][tid], d2c = rd2[sl][tid];
                int   k1 = ri1[sl][tid], k2 = ri2[sl][tid];
                if (d1c < m1) {
                    float n2; int n2i;
                    if (m1 <= d2c) { n2 = m1; n2i = j1; } else { n2 = d2c; n2i = k2; }
                    m1 = d1c; j1 = k1; m2 = n2; j2 = n2i;
                } else if (d1c < m2) { m2 = d1c; j2 = k1; }
            }
            sel[tid]  = j1;
            cand[tid] = (m2 - m1 < 1e-2f) ? j2 : -1;
        }
        __syncthreads();

        if (tid < 8 && cand[tid] >= 0) {   // fp64 rescore of near-tie (index tiebreak)
            int k1 = sel[tid], k2 = cand[tid];
            const float* e1p = vq + ((size_t)s * 2048 + k1) * 128;
            const float* e2p = vq + ((size_t)s * 2048 + k2) * 128;
            double t1 = 0.0, t2 = 0.0;
            for (int d = 0; d < 128; ++d) {
                double z  = (double)s_zcur[tid][d];
                double e1 = (double)e1p[d], e2 = (double)e2p[d];
                t1 += e1 * e1 - 2.0 * e1 * z;
                t2 += e2 * e2 - 2.0 * e2 * z;
            }
            if (t2 < t1 || (t2 == t1 && k2 < k1)) sel[tid] = k2;
        }
        __syncthreads();

        int k = sel[b];
        float4 e = ((const float4*)vq)[((size_t)s * 2048 + k) * 32 + ow];
        // loss partial: (e - z_cur)^2 on owned dims (z_cur still pre-update in LDS)
        {
            int d = ow * 4;
            float4 z4 = *(const float4*)&s_zcur[b][d];
            float f0 = e.x - z4.x, f1 = e.y - z4.y;
            float f2 = e.z - z4.z, f3 = e.w - z4.w;
            rd1[ow][b] = f0*f0 + f1*f1 + f2*f2 + f3*f3;
        }
        // state update, reference rounding order: zqsum += e; resid += lat[s+1]; zcur = resid - zqsum
        {
            int d = ow * 4;
            float4 zq = *(float4*)&s_zqsum[b][d];
            zq.x += e.x; zq.y += e.y; zq.z += e.z; zq.w += e.w;
            *(float4*)&s_zqsum[b][d] = zq;
            if (s < 3) {
                float4 lv = ((const float4*)latents)[li * 128 + (size_t)(s + 1) * 32 + ow];
                float4 rs = *(float4*)&s_resid[b][d];
                rs.x += lv.x; rs.y += lv.y; rs.z += lv.z; rs.w += lv.w;
                *(float4*)&s_resid[b][d] = rs;
                float4 zcn;
                zcn.x = rs.x - zq.x; zcn.y = rs.y - zq.y;
                zcn.z = rs.z - zq.z; zcn.w = rs.w - zq.w;
                *(float4*)&s_zcur[b][d] = zcn;
            }
        }
        __syncthreads();
        if (tid < 8) {
            float l = 0.f;
            for (int sl = 0; sl < 32; ++sl) l += rd1[sl][tid];
            loss_local += l;
        }
        __syncthreads();
    }

    // write z_q_sum (coalesced) and per-block loss partial
    for (int u = tid; u < 1024; u += 256)
        zqsum_g[(size_t)blockIdx.x * 1024 + u] = ((const float*)s_zqsum)[u];
    if (tid < 8) lossb[tid] = loss_local;
    __syncthreads();
    if (tid == 0) {
        float l = 0.f;
        #pragma unroll
        for (int i = 0; i < 8; ++i) l += lossb[i];
        lpartial[blockIdx.x] = l;
    }
}

// ---------------------------------------------------------------- betas (fp32 VALU -> bf16)
// grid (256,5) x 128: 16 batch rows/block, thread t -> h = t and t+128
__global__ __launch_bounds__(128) void betas_kernel(const float* __restrict__ zqsum,
                                                    const float* __restrict__ mod_W,
                                                    const float* __restrict__ mod_b,
                                                    u16* __restrict__ betas) {
    int bg = blockIdx.x, l = blockIdx.y, t = threadIdx.x;
    __shared__ float zq[16][128];
    for (int u = t; u < 2048; u += 128) ((float*)zq)[u] = zqsum[(size_t)bg * 2048 + u];
    __syncthreads();

    float acc0[16], acc1[16];
    #pragma unroll
    for (int i = 0; i < 16; ++i) { acc0[i] = 0.f; acc1[i] = 0.f; }

    const float4* w0 = (const float4*)(mod_W + ((size_t)l * 256 + t) * 128);
    const float4* w1 = (const float4*)(mod_W + ((size_t)l * 256 + t + 128) * 128);
    #pragma unroll
    for (int c = 0; c < 32; ++c) {
        float4 wa = w0[c], wb = w1[c];
        #pragma unroll
        for (int bb = 0; bb < 16; ++bb) {
            float4 za = *(const float4*)&zq[bb][c * 4];
            acc0[bb] += wa.x * za.x + wa.y * za.y + wa.z * za.z + wa.w * za.w;
            acc1[bb] += wb.x * za.x + wb.y * za.y + wb.z * za.z + wb.w * za.w;
        }
    }
    float bias0 = mod_b[l * 256 + t], bias1 = mod_b[l * 256 + t + 128];
    #pragma unroll
    for (int bb = 0; bb < 16; ++bb) {
        size_t o = ((size_t)l * 4096 + bg * 16 + bb) * 256;
        betas[o + t]       = f2b(acc0[bb] + bias0);
        betas[o + t + 128] = f2b(acc1[bb] + bias1);
    }
}

// ---------------------------------------------------------------- fused MLP (bf16 MFMA)
// one block per image (4096 blocks), 256 threads = 4 waves; wave w covers weight
// cols [w*64, w*64+64). MFMA operands: A = weight rows (global), B = activation
// rows (LDS) -> D row dim = weight col (q*4+rr), col dim = activation row (r16),
// so each lane's 4 rr-values are consecutive n at fixed m: epilogue = ds_write_b64.
__global__ __launch_bounds__(256, 4) void mlp_kernel(const float* __restrict__ coords,
                                                     const u16* __restrict__ w0pad,
                                                     const float* __restrict__ dec_b0,
                                                     const u16* __restrict__ dwh,
                                                     const float* __restrict__ dec_bh,
                                                     const float* __restrict__ last_W,
                                                     const float* __restrict__ last_b,
                                                     const u16* __restrict__ betas,
                                                     float* __restrict__ out) {
    __shared__ __align__(16) u16 X[64 * XS];
    int b = blockIdx.x;
    int tid = threadIdx.x;
    int lane = tid & 63, wv = tid >> 6;
    int q = lane >> 4, r16 = lane & 15;
    int nbase = wv * 64;

    // positional encoding: enc = [c0,c1, sin(c0*f), sin(c1*f), cos(c0*f), cos(c1*f)], pad to 64
    {
        int m = tid & 63, g = tid >> 6;
        float c0 = coords[((b << 6) + m) * 2 + 0];
        float c1 = coords[((b << 6) + m) * 2 + 1];
        u16* row = &X[m * XS];
        if (g == 0) {
            row[0] = f2b(c0); row[1] = f2b(c1);
            #pragma unroll
            for (int c = 42; c < 64; ++c) row[c] = 0;
            #pragma unroll
            for (int f = 0; f < 10; ++f) {
                float pf = 3.14159265358979323846f * (float)(1 << f);
                row[32 + f] = f2b(cosf(c1 * pf));
            }
        } else if (g == 1) {
            #pragma unroll
            for (int f = 0; f < 10; ++f) {
                float pf = 3.14159265358979323846f * (float)(1 << f);
                row[2 + f] = f2b(sinf(c0 * pf));
            }
        } else if (g == 2) {
            #pragma unroll
            for (int f = 0; f < 10; ++f) {
                float pf = 3.14159265358979323846f * (float)(1 << f);
                row[12 + f] = f2b(sinf(c1 * pf));
            }
        } else {
            #pragma unroll
            for (int f = 0; f < 10; ++f) {
                float pf = 3.14159265358979323846f * (float)(1 << f);
                row[22 + f] = f2b(cosf(c0 * pf));
            }
        }
    }
    __syncthreads();

    f32x4 acc[4][4];   // [nt][mt]

    auto gemm = [&](const u16* W, int Kdim, int wstride) {
        #pragma unroll
        for (int nt = 0; nt < 4; ++nt)
            #pragma unroll
            for (int mt = 0; mt < 4; ++mt) {
                f32x4 z = {0.f, 0.f, 0.f, 0.f};
                acc[nt][mt] = z;
            }
        for (int kc = 0; kc < Kdim; kc += 32) {
            short8 afr[4], bfr[4];
            #pragma unroll
            for (int nt = 0; nt < 4; ++nt)   // weights
                afr[nt] = *(const short8*)&W[(size_t)(nbase + nt * 16 + r16) * wstride + kc + q * 8];
            #pragma unroll
            for (int mt = 0; mt < 4; ++mt)   // activations
                bfr[mt] = *(const short8*)&X[(mt * 16 + r16) * XS + kc + q * 8];
            #pragma unroll
            for (int nt = 0; nt < 4; ++nt)
                #pragma unroll
                for (int mt = 0; mt < 4; ++mt)
                    acc[nt][mt] = __builtin_amdgcn_mfma_f32_16x16x32_bf16(
                        afr[nt], bfr[mt], acc[nt][mt], 0, 0, 0);
        }
    };

    auto epilogue = [&](const float* bias, const u16* beta_l) {
        // per-lane bias+beta for its 4 consecutive n per nt
        float bv[4][4];
        #pragma unroll
        for (int nt = 0; nt < 4; ++nt) {
            int n0 = nbase + nt * 16 + q * 4;
            float4 bs = *(const float4*)&bias[n0];
            bv[nt][0] = bs.x + b2f(beta_l[n0 + 0]);
            bv[nt][1] = bs.y + b2f(beta_l[n0 + 1]);
            bv[nt][2] = bs.z + b2f(beta_l[n0 + 2]);
            bv[nt][3] = bs.w + b2f(beta_l[n0 + 3]);
        }
        __syncthreads();   // all waves done reading X
        #pragma unroll
        for (int mt = 0; mt < 4; ++mt) {
            int m = mt * 16 + r16;
            #pragma unroll
            for (int nt = 0; nt < 4; ++nt) {
                int n0 = nbase + nt * 16 + q * 4;
                float v0 = fmaxf(acc[nt][mt][0] + bv[nt][0], 0.f);
                float v1 = fmaxf(acc[nt][mt][1] + bv[nt][1], 0.f);
                float v2 = fmaxf(acc[nt][mt][2] + bv[nt][2], 0.f);
                float v3 = fmaxf(acc[nt][mt][3] + bv[nt][3], 0.f);
                uint2 pk;
                pk.x = (u32)f2b(v0) | ((u32)f2b(v1) << 16);
                pk.y = (u32)f2b(v2) | ((u32)f2b(v3) << 16);
                *(uint2*)&X[m * XS + n0] = pk;
            }
        }
        __syncthreads();
    };

    gemm(w0pad, 64, 64);
    epilogue(dec_b0, betas + (size_t)b * 256);

    for (int l = 1; l < 5; ++l) {
        gemm(dwh + (size_t)(l - 1) * 65536, 256, 256);
        epilogue(dec_bh + (size_t)(l - 1) * 256, betas + ((size_t)l * 4096 + b) * 256);
    }

    // last layer: 64 rows x 3 outputs, fp32 VALU, fp32 store
    if (tid < 192) {
        int rr = tid / 3, v = tid - rr * 3;
        float a = 0.f;
        #pragma unroll
        for (int d = 0; d < 256; d += 8) {
            #pragma unroll
            for (int j = 0; j < 8; ++j)
                a += b2f(X[rr * XS + d + j]) * last_W[v * 256 + d + j];
        }
        out[((size_t)b * 64 + rr) * 3 + v] = a + last_b[v];
    }
}

// ---------------------------------------------------------------- loss finalize
__global__ __launch_bounds__(64) void finalize_kernel(const float* __restrict__ lpartial,
                                                      float* __restrict__ out) {
    int t = threadIdx.x;
    float s = 0.f;
    for (int i = t; i < 512; i += 64) s += lpartial[i];
    #pragma unroll
    for (int off = 32; off; off >>= 1) s += __shfl_down(s, off);
    if (t == 0) out[786432] = 0.25f * s * (1.f / (4096.f * 128.f));
}

extern "C" void kernel_launch(void* const* d_in, const int* in_sizes, int n_in,
                              void* d_out, int out_size, void* d_ws, size_t ws_size,
                              hipStream_t stream) {
    const float* coords  = (const float*)d_in[0];
    const int*   lidx    = (const int*)d_in[1];
    const float* latents = (const float*)d_in[2];
    const float* vq      = (const float*)d_in[3];
    const float* mod_W   = (const float*)d_in[4];
    const float* mod_b   = (const float*)d_in[5];
    const float* dec_W0  = (const float*)d_in[6];
    const float* dec_b0  = (const float*)d_in[7];
    const float* dec_Wh  = (const float*)d_in[8];
    const float* dec_bh  = (const float*)d_in[9];
    const float* last_W  = (const float*)d_in[10];
    const float* last_b  = (const float*)d_in[11];
    float* out = (float*)d_out;

    float* wsf      = (float*)d_ws;
    float* lpartial = wsf + WS_LPART;
    float* enorm    = wsf + WS_ENORM;
    float* zqsum    = wsf + WS_ZQSUM;
    u16*   betas    = (u16*)(wsf + WS_BETAS);
    u16*   w0pad    = (u16*)(wsf + WS_W0PAD);
    u16*   dwh      = (u16*)(wsf + WS_DWH);

    enorm_kernel<<<8192, 64, 0, stream>>>(vq, enorm);
    padw0_kernel<<<64, 256, 0, stream>>>(dec_W0, w0pad);
    dwh_kernel<<<1024, 256, 0, stream>>>(dec_Wh, dwh);
    vq_kernel<<<512, 256, 0, stream>>>(lidx, latents, vq, enorm, zqsum, lpartial);
    betas_kernel<<<dim3(256, 5), 128, 0, stream>>>(zqsum, mod_W, mod_b, betas);
    mlp_kernel<<<4096, 256, 0, stream>>>(coords, w0pad, dec_b0, dwh, dec_bh,
                                         last_W, last_b, betas, out);
    finalize_kernel<<<1, 64, 0, stream>>>(lpartial, out);
}